// Round 3
// baseline (578.960 us; speedup 1.0000x reference)
//
#include <hip/hip_runtime.h>
#include <hip/hip_bf16.h>
#include <cstdint>
#include <cstddef>

// Problem constants (LlamaAttention: B=2,S=1024,P=1024,H=4096,NQ=32,NKV=8,D=128)
#define B_    2
#define S_    1024
#define P_    1024
#define T_    2048      // P + S
#define H_    4096
#define NQ_   32
#define NKV_  8
#define D_    128
#define QKVN_ 6144      // (NQ + 2*NKV) * D
#define SCALE_ 0.08838834764831845f  // 1/sqrt(128)

typedef unsigned short u16;
typedef short  bf16x8 __attribute__((ext_vector_type(8)));   // 8 bf16 = 4 VGPR (MFMA A/B frag)
typedef float  f32x4  __attribute__((ext_vector_type(4)));   // MFMA C/D frag

__device__ __forceinline__ float bf2f(u16 u) {
  union { unsigned u; float f; } x; x.u = ((unsigned)u) << 16; return x.f;
}
__device__ __forceinline__ u16 f2bf(float f) {
  union { float f; unsigned u; } x; x.f = f;
  unsigned r = (x.u + 0x7fffu + ((x.u >> 16) & 1u)) >> 16;   // RNE
  return (u16)r;
}

// async global->LDS, 16B per lane. LDS dest must be wave-uniform base + lane*16
// (chunk = tid + i*256 guarantees per-lane LDS addr = firstlane_base + lane*16).
// Global src IS per-lane -> source-side XOR swizzle works (m173 pattern).
__device__ __forceinline__ void gload16(const void* g, void* l) {
  __builtin_amdgcn_global_load_lds(
      (const __attribute__((address_space(1))) unsigned int*)g,
      (__attribute__((address_space(3))) unsigned int*)l, 16, 0, 0);
}

// ---------------- hidden f32 -> bf16 ----------------
__global__ void k_f32_to_bf16(const float* __restrict__ in, u16* __restrict__ out, int n4) {
  int i = blockIdx.x * blockDim.x + threadIdx.x;
  if (i >= n4) return;
  float4 v = ((const float4*)in)[i];
  union { u16 s[4]; uint2 v; } o;
  o.s[0] = f2bf(v.x); o.s[1] = f2bf(v.y); o.s[2] = f2bf(v.z); o.s[3] = f2bf(v.w);
  ((uint2*)out)[i] = o.v;
}

// ---------------- w[K][N] f32 -> wt[N][K] bf16 (64x64 LDS tile transpose) ----------------
__global__ void k_wtrans(const float* __restrict__ w, u16* __restrict__ wt, int K, int N) {
  __shared__ __align__(16) u16 tile[64][66];   // pad 66: conflict-free column reads
  const int n0 = blockIdx.x * 64;
  const int k0 = blockIdx.y * 64;
  const int tid = threadIdx.x;
  const int c = tid & 63;
  const int r4 = tid >> 6;
#pragma unroll
  for (int i = 0; i < 16; ++i) {
    int rr = r4 * 16 + i;
    tile[rr][c] = f2bf(w[(size_t)(k0 + rr) * N + n0 + c]);
  }
  __syncthreads();
#pragma unroll
  for (int i = 0; i < 16; ++i) {
    int rr = r4 * 16 + i;
    wt[(size_t)(n0 + rr) * K + k0 + c] = tile[c][rr];
  }
}

// ---------------- GEMM: C[M,N] = A[M,K](bf16) @ Bt[N,K](bf16)^T, fp32 accum ----------------
// 128x128 tile, BK=64, 4 waves (2x2), each wave 64x64 via 4x4 frags of 16x16x32.
// LDS XOR-swizzle (chunk ^= row&7) applied on the GLOBAL source of global_load_lds
// and on ds_read addresses -> conflict-free ds_read_b128 (T2, both-sides rule #21).
template<bool BF16OUT>
__global__ __launch_bounds__(256, 2)
void k_gemm(const u16* __restrict__ A, const u16* __restrict__ Bt,
            void* __restrict__ Cv, int M, int N, int K) {
  __shared__ __align__(16) u16 As[128 * 64];   // 16KB, rows 128B = 8 chunks of 16B
  __shared__ __align__(16) u16 Bs[128 * 64];
  const int tid = threadIdx.x;
  const int lane = tid & 63;
  const int wv = tid >> 6;
  const int wm = wv >> 1, wn = wv & 1;
  const int m0 = blockIdx.y * 128;
  const int n0 = blockIdx.x * 128;
  const int l15 = lane & 15, l4 = lane >> 4;

  f32x4 acc[4][4] = {};
  const int nk = K >> 6;
  int srow[4], scol[4];
#pragma unroll
  for (int i = 0; i < 4; ++i) {
    int chunk = tid + i * 256;           // 1024 chunks per tile
    srow[i] = chunk >> 3;
    scol[i] = (chunk & 7) ^ (srow[i] & 7);
  }
  for (int kt = 0; kt < nk; ++kt) {
    __syncthreads();
#pragma unroll
    for (int i = 0; i < 4; ++i) {
      int chunk = tid + i * 256;
      gload16(A  + (size_t)(m0 + srow[i]) * K + kt * 64 + scol[i] * 8, &As[chunk * 8]);
      gload16(Bt + (size_t)(n0 + srow[i]) * K + kt * 64 + scol[i] * 8, &Bs[chunk * 8]);
    }
    __syncthreads();   // compiler emits vmcnt(0) before s_barrier -> LDS ready
    bf16x8 af[4][2], bfr[4][2];
#pragma unroll
    for (int mt = 0; mt < 4; ++mt) {
      int r = wm * 64 + mt * 16 + l15;
#pragma unroll
      for (int ks = 0; ks < 2; ++ks) {
        int cc = (ks * 4 + l4) ^ (r & 7);
        af[mt][ks] = *(const bf16x8*)(&As[r * 64 + cc * 8]);
      }
    }
#pragma unroll
    for (int nt = 0; nt < 4; ++nt) {
      int r = wn * 64 + nt * 16 + l15;
#pragma unroll
      for (int ks = 0; ks < 2; ++ks) {
        int cc = (ks * 4 + l4) ^ (r & 7);
        bfr[nt][ks] = *(const bf16x8*)(&Bs[r * 64 + cc * 8]);
      }
    }
#pragma unroll
    for (int mt = 0; mt < 4; ++mt)
#pragma unroll
      for (int nt = 0; nt < 4; ++nt)
#pragma unroll
        for (int ks = 0; ks < 2; ++ks)
          acc[mt][nt] = __builtin_amdgcn_mfma_f32_16x16x32_bf16(
              af[mt][ks], bfr[nt][ks], acc[mt][nt], 0, 0, 0);
  }
  // epilogue: D[m][n]: col = lane&15, row = 4*(lane>>4)+i  [measured m89/m91]
#pragma unroll
  for (int mt = 0; mt < 4; ++mt)
#pragma unroll
    for (int nt = 0; nt < 4; ++nt)
#pragma unroll
      for (int i = 0; i < 4; ++i) {
        int row = m0 + wm * 64 + mt * 16 + l4 * 4 + i;
        int col = n0 + wn * 64 + nt * 16 + l15;
        size_t off = (size_t)row * N + col;
        if (BF16OUT) ((u16*)Cv)[off] = f2bf(acc[mt][nt][i]);
        else         ((float*)Cv)[off] = acc[mt][nt][i];
      }
}

// ---------------- RoPE + scatter into head-major layouts ----------------
// q (scaled by 1/sqrt(D)) -> Q[B][NQ][S][D]; new k -> Kall[B][NKV][P+s][D];
// fp32 k_cache -> Kall[B][NKV][t][D]
__global__ void k_rope_scatter(const u16* __restrict__ qkv,
                               const float* __restrict__ cosb, const float* __restrict__ sinb,
                               const float* __restrict__ kcache,
                               u16* __restrict__ Q, u16* __restrict__ Kall) {
  const int gsz = gridDim.x * blockDim.x;
  const int i0 = blockIdx.x * blockDim.x + threadIdx.x;
  // q rope pairs: 2*1024*32*64 = 2^22
  for (int i = i0; i < B_ * S_ * NQ_ * 64; i += gsz) {
    int d = i & 63, hh = (i >> 6) & 31, s = (i >> 11) & 1023, b = i >> 21;
    const u16* row = qkv + (size_t)(b * S_ + s) * QKVN_ + hh * D_;
    float x1 = bf2f(row[d]), x2 = bf2f(row[d + 64]);
    float c = cosb[s * D_ + d], sn = sinb[s * D_ + d];   // cos/sin duplicated halves
    u16* q = Q + (size_t)((b * NQ_ + hh) * S_ + s) * D_;
    q[d]      = f2bf((x1 * c - x2 * sn) * SCALE_);
    q[d + 64] = f2bf((x2 * c + x1 * sn) * SCALE_);
  }
  // k rope pairs: 2*1024*8*64 = 2^20
  for (int i = i0; i < B_ * S_ * NKV_ * 64; i += gsz) {
    int d = i & 63, kh = (i >> 6) & 7, s = (i >> 9) & 1023, b = i >> 19;
    const u16* row = qkv + (size_t)(b * S_ + s) * QKVN_ + NQ_ * D_ + kh * D_;
    float x1 = bf2f(row[d]), x2 = bf2f(row[d + 64]);
    float c = cosb[s * D_ + d], sn = sinb[s * D_ + d];
    u16* kd = Kall + (size_t)((b * NKV_ + kh) * T_ + P_ + s) * D_;
    kd[d]      = f2bf(x1 * c - x2 * sn);
    kd[d + 64] = f2bf(x2 * c + x1 * sn);
  }
  // k cache copy: 2*1024*8*128 = 2^21
  for (int i = i0; i < B_ * P_ * NKV_ * D_; i += gsz) {
    int d = i & 127, kh = (i >> 7) & 7, t = (i >> 10) & 1023, b = i >> 20;
    float x = kcache[(size_t)((b * P_ + t) * NKV_ + kh) * D_ + d];
    Kall[(size_t)((b * NKV_ + kh) * T_ + t) * D_ + d] = f2bf(x);
  }
}

// ---------------- V -> transposed Vt[B][NKV][D][T] (64x64 LDS tile transpose) ----------------
__global__ void k_vbuild(const u16* __restrict__ qkv, const float* __restrict__ vcache,
                         u16* __restrict__ Vt) {
  __shared__ __align__(16) u16 tile[64][66];
  const int t0 = blockIdx.x * 64;
  const int d0 = blockIdx.y * 64;
  const int bkh = blockIdx.z;
  const int b = bkh >> 3, kh = bkh & 7;
  const int tid = threadIdx.x;
  const int c = tid & 63, r4 = tid >> 6;
#pragma unroll
  for (int i = 0; i < 16; ++i) {
    int rr = r4 * 16 + i;
    int t = t0 + rr;
    float x;
    if (t < P_) x = vcache[(size_t)((b * P_ + t) * NKV_ + kh) * D_ + d0 + c];
    else        x = bf2f(qkv[(size_t)(b * S_ + (t - P_)) * QKVN_ + (NQ_ + NKV_) * D_ + kh * D_ + d0 + c]);
    tile[rr][c] = f2bf(x);
  }
  __syncthreads();
  u16* out = Vt + ((size_t)(b * NKV_ + kh) * D_ + d0) * T_ + t0;
#pragma unroll
  for (int i = 0; i < 16; ++i) {
    int rr = r4 * 16 + i;                  // d offset
    out[(size_t)rr * T_ + c] = tile[c][rr];
  }
}

// ---------------- flash attention ----------------
// Grid (S/128, NQ, B). 4 waves x 32 q-rows. KV tiles of 64 staged via
// global_load_lds with source-side XOR swizzle; online softmax in-register;
// P relayout (D-frag -> A-frag) through per-wave swizzled LDS.
__global__ __launch_bounds__(256, 2)
void k_attn(const u16* __restrict__ Q, const u16* __restrict__ Kall,
            const u16* __restrict__ Vt, u16* __restrict__ O) {
  __shared__ __align__(16) u16 Ks[64 * 128];     // [t][d] 16KB, 16 chunks/row
  __shared__ __align__(16) u16 Vs[128 * 64];     // [d][t] 16KB, 8 chunks/row
  __shared__ __align__(16) u16 Ps[4][32 * 64];   // per-wave P, 4x4KB
  const int sb = blockIdx.x;       // 0..7
  const int h  = blockIdx.y;       // 0..31
  const int b  = blockIdx.z;       // 0..1
  const int kh = h >> 2;           // GQA: G=4
  const int tid = threadIdx.x;
  const int lane = tid & 63, wv = tid >> 6;
  const int l15 = lane & 15, l4 = lane >> 4;
  const int s0 = sb * 128;
  const int rowbase = s0 + wv * 32;

  // Q frags held in registers for the whole KV loop (Q pre-scaled by 1/sqrt(D))
  const u16* qbase = Q + (size_t)(b * NQ_ + h) * S_ * D_;
  bf16x8 qf[2][4];
#pragma unroll
  for (int mt = 0; mt < 2; ++mt)
#pragma unroll
    for (int ks = 0; ks < 4; ++ks)
      qf[mt][ks] = *(const bf16x8*)(qbase + (size_t)(rowbase + mt * 16 + l15) * D_ + ks * 32 + l4 * 8);

  f32x4 acco[2][8] = {};
  float mrun[2][4], lrun[2][4];
#pragma unroll
  for (int mt = 0; mt < 2; ++mt)
#pragma unroll
    for (int i = 0; i < 4; ++i) { mrun[mt][i] = -1e30f; lrun[mt][i] = 0.f; }

  const u16* kbase = Kall + (size_t)(b * NKV_ + kh) * T_ * D_;
  const u16* vbase = Vt   + (size_t)(b * NKV_ + kh) * D_ * T_;
  const int ntiles = min(32, 2 * sb + 18);   // last t = s0+127+P

  for (int tt = 0; tt < ntiles; ++tt) {
    const int t0 = tt * 64;
    __syncthreads();   // prev compute done before LDS overwrite
#pragma unroll
    for (int i = 0; i < 4; ++i) {
      int chunk = tid + i * 256;
      int kr = chunk >> 4, kc = chunk & 15;
      gload16(kbase + (size_t)(t0 + kr) * D_ + (kc ^ (kr & 7)) * 8, &Ks[chunk * 8]);
      int vr = chunk >> 3, vc = chunk & 7;
      gload16(vbase + (size_t)vr * T_ + t0 + (vc ^ (vr & 7)) * 8, &Vs[chunk * 8]);
    }
    __syncthreads();

    // S = Q @ K^T  (32 MFMAs, 16 swizzled ds_read_b128)
    f32x4 accs[2][4] = {};
#pragma unroll
    for (int tb = 0; tb < 4; ++tb) {
      int r = tb * 16 + l15;
#pragma unroll
      for (int ks = 0; ks < 4; ++ks) {
        int cc = (ks * 4 + l4) ^ (r & 7);
        bf16x8 kf = *(const bf16x8*)(&Ks[r * 128 + cc * 8]);
#pragma unroll
        for (int mt = 0; mt < 2; ++mt)
          accs[mt][tb] = __builtin_amdgcn_mfma_f32_16x16x32_bf16(qf[mt][ks], kf, accs[mt][tb], 0, 0, 0);
      }
    }
    // causal mask (only last two tiles can be partial: P,S multiples of 64)
    if (tt >= 2 * sb + 16) {
#pragma unroll
      for (int mt = 0; mt < 2; ++mt)
#pragma unroll
        for (int tb = 0; tb < 4; ++tb)
#pragma unroll
          for (int i = 0; i < 4; ++i) {
            int srow = rowbase + mt * 16 + l4 * 4 + i;
            int tcol = t0 + tb * 16 + l15;
            if (tcol > srow + P_) accs[mt][tb][i] = -1e30f;
          }
    }
    // online softmax (rows live in 16 consecutive lanes -> shfl_xor 1,2,4,8)
#pragma unroll
    for (int mt = 0; mt < 2; ++mt) {
      float al[4];
#pragma unroll
      for (int i = 0; i < 4; ++i) {
        float v = fmaxf(fmaxf(accs[mt][0][i], accs[mt][1][i]),
                        fmaxf(accs[mt][2][i], accs[mt][3][i]));
        v = fmaxf(v, __shfl_xor(v, 1));
        v = fmaxf(v, __shfl_xor(v, 2));
        v = fmaxf(v, __shfl_xor(v, 4));
        v = fmaxf(v, __shfl_xor(v, 8));
        float mn = fmaxf(mrun[mt][i], v);
        al[i] = __expf(mrun[mt][i] - mn);
        mrun[mt][i] = mn;
      }
      float rs[4] = {0.f, 0.f, 0.f, 0.f};
#pragma unroll
      for (int tb = 0; tb < 4; ++tb)
#pragma unroll
        for (int i = 0; i < 4; ++i) {
          float p = __expf(accs[mt][tb][i] - mrun[mt][i]);
          accs[mt][tb][i] = p;
          rs[i] += p;
        }
#pragma unroll
      for (int i = 0; i < 4; ++i) {
        rs[i] += __shfl_xor(rs[i], 1);
        rs[i] += __shfl_xor(rs[i], 2);
        rs[i] += __shfl_xor(rs[i], 4);
        rs[i] += __shfl_xor(rs[i], 8);
        lrun[mt][i] = lrun[mt][i] * al[i] + rs[i];
      }
#pragma unroll
      for (int db = 0; db < 8; ++db)
#pragma unroll
        for (int i = 0; i < 4; ++i)
          acco[mt][db][i] *= al[i];
      // P (D-layout) -> swizzled LDS, to be re-read as A-frags
#pragma unroll
      for (int tb = 0; tb < 4; ++tb)
#pragma unroll
        for (int i = 0; i < 4; ++i) {
          int r = mt * 16 + l4 * 4 + i;
          int col = tb * 16 + l15;
          int cc = (col >> 3) ^ (r & 7);
          Ps[wv][r * 64 + cc * 8 + (col & 7)] = f2bf(accs[mt][tb][i]);
        }
    }
    // O += P @ V   (per-wave LDS: same-wave DS ops are in-order; no barrier needed)
#pragma unroll
    for (int ks = 0; ks < 2; ++ks) {
      bf16x8 pf[2];
#pragma unroll
      for (int mt = 0; mt < 2; ++mt) {
        int r = mt * 16 + l15;
        int cc = (ks * 4 + l4) ^ (r & 7);
        pf[mt] = *(const bf16x8*)(&Ps[wv][r * 64 + cc * 8]);
      }
#pragma unroll
      for (int db = 0; db < 8; ++db) {
        int r = db * 16 + l15;
        int cc = (ks * 4 + l4) ^ (r & 7);
        bf16x8 vf = *(const bf16x8*)(&Vs[r * 64 + cc * 8]);
#pragma unroll
        for (int mt = 0; mt < 2; ++mt)
          acco[mt][db] = __builtin_amdgcn_mfma_f32_16x16x32_bf16(pf[mt], vf, acco[mt][db], 0, 0, 0);
      }
    }
  }
  // epilogue: O / l, -> bf16 attn_out [B*S][NQ*D]
#pragma unroll
  for (int mt = 0; mt < 2; ++mt)
#pragma unroll
    for (int db = 0; db < 8; ++db)
#pragma unroll
      for (int i = 0; i < 4; ++i) {
        int srow = rowbase + mt * 16 + l4 * 4 + i;
        int d = db * 16 + l15;
        float o = acco[mt][db][i] / lrun[mt][i];
        O[(size_t)(b * S_ + srow) * (NQ_ * D_) + h * D_ + d] = f2bf(o);
      }
}

// ---------------- launcher ----------------
extern "C" void kernel_launch(void* const* d_in, const int* in_sizes, int n_in,
                              void* d_out, int out_size, void* d_ws, size_t ws_size,
                              hipStream_t stream) {
  const float* hidden = (const float*)d_in[0];  // [2,1024,4096]
  const float* w_qkv  = (const float*)d_in[1];  // [4096,6144]
  const float* w_o    = (const float*)d_in[2];  // [4096,4096]
  const float* cosb   = (const float*)d_in[3];  // [1024,128]
  const float* sinb   = (const float*)d_in[4];
  const float* kc     = (const float*)d_in[5];  // [2,1024,8,128]
  const float* vc     = (const float*)d_in[6];
  float* out = (float*)d_out;                   // [2,1024,4096] fp32

  // workspace layout (bytes). wot reuses [hid|qkv-head] region — both dead
  // by the time k_wtrans(w_o) runs (same-stream serialization).
  char* ws = (char*)d_ws;
  u16* wqkvt = (u16*)(ws + 0);           // 6144*4096*2 = 50331648
  u16* hid   = (u16*)(ws + 50331648);    // 2048*4096*2 = 16777216
  u16* qkv   = (u16*)(ws + 67108864);    // 2048*6144*2 = 25165824
  u16* wot   = (u16*)(ws + 50331648);    // 4096*4096*2 = 33554432 (reuse)
  u16* qrope = (u16*)(ws + 92274688);    // 16777216
  u16* kall  = (u16*)(ws + 109051904);   // 8388608
  u16* vallt = (u16*)(ws + 117440512);   // 8388608
  u16* attno = (u16*)(ws + 125829120);   // 16777216  (total 142606336 B)

  k_wtrans<<<dim3(QKVN_ / 64, H_ / 64), 256, 0, stream>>>(w_qkv, wqkvt, H_, QKVN_);
  k_f32_to_bf16<<<(B_ * S_ * H_ / 4 + 255) / 256, 256, 0, stream>>>(hidden, hid, B_ * S_ * H_ / 4);
  k_gemm<true><<<dim3(QKVN_ / 128, (B_ * S_) / 128), 256, 0, stream>>>(
      hid, wqkvt, qkv, B_ * S_, QKVN_, H_);
  k_rope_scatter<<<2048, 256, 0, stream>>>(qkv, cosb, sinb, kc, qrope, kall);
  k_vbuild<<<dim3(T_ / 64, D_ / 64, B_ * NKV_), 256, 0, stream>>>(qkv, vc, vallt);
  k_wtrans<<<dim3(H_ / 64, H_ / 64), 256, 0, stream>>>(w_o, wot, H_, H_);
  k_attn<<<dim3(S_ / 128, NQ_, B_), 256, 0, stream>>>(qrope, kall, vallt, attno);
  k_gemm<false><<<dim3(H_ / 128, (B_ * S_) / 128), 256, 0, stream>>>(
      attno, wot, out, B_ * S_, H_, H_);
}

// Round 4
// 555.279 us; speedup vs baseline: 1.0426x; 1.0426x over previous
//
#include <hip/hip_runtime.h>
#include <hip/hip_bf16.h>
#include <cstdint>
#include <cstddef>

// Problem constants (LlamaAttention: B=2,S=1024,P=1024,H=4096,NQ=32,NKV=8,D=128)
#define B_    2
#define S_    1024
#define P_    1024
#define T_    2048      // P + S
#define H_    4096
#define NQ_   32
#define NKV_  8
#define D_    128
#define QKVN_ 6144      // (NQ + 2*NKV) * D
#define SCALE_ 0.08838834764831845f  // 1/sqrt(128)

typedef unsigned short u16;
typedef short  bf16x8 __attribute__((ext_vector_type(8)));   // 8 bf16 = 4 VGPR (MFMA A/B frag)
typedef float  f32x4  __attribute__((ext_vector_type(4)));   // MFMA C/D frag

__device__ __forceinline__ float bf2f(u16 u) {
  union { unsigned u; float f; } x; x.u = ((unsigned)u) << 16; return x.f;
}
__device__ __forceinline__ u16 f2bf(float f) {
  union { float f; unsigned u; } x; x.f = f;
  unsigned r = (x.u + 0x7fffu + ((x.u >> 16) & 1u)) >> 16;   // RNE
  return (u16)r;
}

// async global->LDS, 16B per lane. LDS dest must be wave-uniform base + lane*16
// (chunk = tid + i*256 guarantees per-lane LDS addr = firstlane_base + lane*16).
// Global src IS per-lane -> source-side XOR swizzle works (m173 pattern).
__device__ __forceinline__ void gload16(const void* g, void* l) {
  __builtin_amdgcn_global_load_lds(
      (const __attribute__((address_space(1))) unsigned int*)g,
      (__attribute__((address_space(3))) unsigned int*)l, 16, 0, 0);
}

// ---------------- hidden f32 -> bf16 ----------------
__global__ void k_f32_to_bf16(const float* __restrict__ in, u16* __restrict__ out, int n4) {
  int i = blockIdx.x * blockDim.x + threadIdx.x;
  if (i >= n4) return;
  float4 v = ((const float4*)in)[i];
  union { u16 s[4]; uint2 v; } o;
  o.s[0] = f2bf(v.x); o.s[1] = f2bf(v.y); o.s[2] = f2bf(v.z); o.s[3] = f2bf(v.w);
  ((uint2*)out)[i] = o.v;
}

// ---------------- w[K][N] f32 -> wt[N][K] bf16 (64x64 LDS tile transpose) ----------------
__global__ void k_wtrans(const float* __restrict__ w, u16* __restrict__ wt, int K, int N) {
  __shared__ __align__(16) u16 tile[64][66];   // pad 66: conflict-free column reads
  const int n0 = blockIdx.x * 64;
  const int k0 = blockIdx.y * 64;
  const int tid = threadIdx.x;
  const int c = tid & 63;
  const int r4 = tid >> 6;
#pragma unroll
  for (int i = 0; i < 16; ++i) {
    int rr = r4 * 16 + i;
    tile[rr][c] = f2bf(w[(size_t)(k0 + rr) * N + n0 + c]);
  }
  __syncthreads();
#pragma unroll
  for (int i = 0; i < 16; ++i) {
    int rr = r4 * 16 + i;
    wt[(size_t)(n0 + rr) * K + k0 + c] = tile[c][rr];
  }
}

// ---------------- GEMM: C[M,N] = A[M,K](bf16) @ Bt[N,K](bf16)^T, fp32 accum ----------------
// 128x128 tile, BK=64, 4 waves (2x2), each wave 64x64 via 4x4 frags of 16x16x32.
// LDS XOR-swizzle (chunk ^= row&7) applied on the GLOBAL source of global_load_lds
// and on ds_read addresses -> conflict-free ds_read_b128 (T2, both-sides rule #21).
// (unchanged this round: m99/m139 measured explicit dbuf neutral on this structure)
template<bool BF16OUT>
__global__ __launch_bounds__(256, 2)
void k_gemm(const u16* __restrict__ A, const u16* __restrict__ Bt,
            void* __restrict__ Cv, int M, int N, int K) {
  __shared__ __align__(16) u16 As[128 * 64];   // 16KB, rows 128B = 8 chunks of 16B
  __shared__ __align__(16) u16 Bs[128 * 64];
  const int tid = threadIdx.x;
  const int lane = tid & 63;
  const int wv = tid >> 6;
  const int wm = wv >> 1, wn = wv & 1;
  const int m0 = blockIdx.y * 128;
  const int n0 = blockIdx.x * 128;
  const int l15 = lane & 15, l4 = lane >> 4;

  f32x4 acc[4][4] = {};
  const int nk = K >> 6;
  int srow[4], scol[4];
#pragma unroll
  for (int i = 0; i < 4; ++i) {
    int chunk = tid + i * 256;           // 1024 chunks per tile
    srow[i] = chunk >> 3;
    scol[i] = (chunk & 7) ^ (srow[i] & 7);
  }
  for (int kt = 0; kt < nk; ++kt) {
    __syncthreads();
#pragma unroll
    for (int i = 0; i < 4; ++i) {
      int chunk = tid + i * 256;
      gload16(A  + (size_t)(m0 + srow[i]) * K + kt * 64 + scol[i] * 8, &As[chunk * 8]);
      gload16(Bt + (size_t)(n0 + srow[i]) * K + kt * 64 + scol[i] * 8, &Bs[chunk * 8]);
    }
    __syncthreads();   // compiler emits vmcnt(0) before s_barrier -> LDS ready
    bf16x8 af[4][2], bfr[4][2];
#pragma unroll
    for (int mt = 0; mt < 4; ++mt) {
      int r = wm * 64 + mt * 16 + l15;
#pragma unroll
      for (int ks = 0; ks < 2; ++ks) {
        int cc = (ks * 4 + l4) ^ (r & 7);
        af[mt][ks] = *(const bf16x8*)(&As[r * 64 + cc * 8]);
      }
    }
#pragma unroll
    for (int nt = 0; nt < 4; ++nt) {
      int r = wn * 64 + nt * 16 + l15;
#pragma unroll
      for (int ks = 0; ks < 2; ++ks) {
        int cc = (ks * 4 + l4) ^ (r & 7);
        bfr[nt][ks] = *(const bf16x8*)(&Bs[r * 64 + cc * 8]);
      }
    }
#pragma unroll
    for (int mt = 0; mt < 4; ++mt)
#pragma unroll
      for (int nt = 0; nt < 4; ++nt)
#pragma unroll
        for (int ks = 0; ks < 2; ++ks)
          acc[mt][nt] = __builtin_amdgcn_mfma_f32_16x16x32_bf16(
              af[mt][ks], bfr[nt][ks], acc[mt][nt], 0, 0, 0);
  }
  // epilogue: D[m][n]: col = lane&15, row = 4*(lane>>4)+i  [measured m89/m91]
#pragma unroll
  for (int mt = 0; mt < 4; ++mt)
#pragma unroll
    for (int nt = 0; nt < 4; ++nt)
#pragma unroll
      for (int i = 0; i < 4; ++i) {
        int row = m0 + wm * 64 + mt * 16 + l4 * 4 + i;
        int col = n0 + wn * 64 + nt * 16 + l15;
        size_t off = (size_t)row * N + col;
        if (BF16OUT) ((u16*)Cv)[off] = f2bf(acc[mt][nt][i]);
        else         ((float*)Cv)[off] = acc[mt][nt][i];
      }
}

// ---------------- RoPE + scatter into head-major layouts ----------------
__global__ void k_rope_scatter(const u16* __restrict__ qkv,
                               const float* __restrict__ cosb, const float* __restrict__ sinb,
                               const float* __restrict__ kcache,
                               u16* __restrict__ Q, u16* __restrict__ Kall) {
  const int gsz = gridDim.x * blockDim.x;
  const int i0 = blockIdx.x * blockDim.x + threadIdx.x;
  for (int i = i0; i < B_ * S_ * NQ_ * 64; i += gsz) {
    int d = i & 63, hh = (i >> 6) & 31, s = (i >> 11) & 1023, b = i >> 21;
    const u16* row = qkv + (size_t)(b * S_ + s) * QKVN_ + hh * D_;
    float x1 = bf2f(row[d]), x2 = bf2f(row[d + 64]);
    float c = cosb[s * D_ + d], sn = sinb[s * D_ + d];
    u16* q = Q + (size_t)((b * NQ_ + hh) * S_ + s) * D_;
    q[d]      = f2bf((x1 * c - x2 * sn) * SCALE_);
    q[d + 64] = f2bf((x2 * c + x1 * sn) * SCALE_);
  }
  for (int i = i0; i < B_ * S_ * NKV_ * 64; i += gsz) {
    int d = i & 63, kh = (i >> 6) & 7, s = (i >> 9) & 1023, b = i >> 19;
    const u16* row = qkv + (size_t)(b * S_ + s) * QKVN_ + NQ_ * D_ + kh * D_;
    float x1 = bf2f(row[d]), x2 = bf2f(row[d + 64]);
    float c = cosb[s * D_ + d], sn = sinb[s * D_ + d];
    u16* kd = Kall + (size_t)((b * NKV_ + kh) * T_ + P_ + s) * D_;
    kd[d]      = f2bf(x1 * c - x2 * sn);
    kd[d + 64] = f2bf(x2 * c + x1 * sn);
  }
  for (int i = i0; i < B_ * P_ * NKV_ * D_; i += gsz) {
    int d = i & 127, kh = (i >> 7) & 7, t = (i >> 10) & 1023, b = i >> 20;
    float x = kcache[(size_t)((b * P_ + t) * NKV_ + kh) * D_ + d];
    Kall[(size_t)((b * NKV_ + kh) * T_ + t) * D_ + d] = f2bf(x);
  }
}

// ---------------- V -> transposed Vt[B][NKV][D][T] (64x64 LDS tile transpose) ----------------
__global__ void k_vbuild(const u16* __restrict__ qkv, const float* __restrict__ vcache,
                         u16* __restrict__ Vt) {
  __shared__ __align__(16) u16 tile[64][66];
  const int t0 = blockIdx.x * 64;
  const int d0 = blockIdx.y * 64;
  const int bkh = blockIdx.z;
  const int b = bkh >> 3, kh = bkh & 7;
  const int tid = threadIdx.x;
  const int c = tid & 63, r4 = tid >> 6;
#pragma unroll
  for (int i = 0; i < 16; ++i) {
    int rr = r4 * 16 + i;
    int t = t0 + rr;
    float x;
    if (t < P_) x = vcache[(size_t)((b * P_ + t) * NKV_ + kh) * D_ + d0 + c];
    else        x = bf2f(qkv[(size_t)(b * S_ + (t - P_)) * QKVN_ + (NQ_ + NKV_) * D_ + kh * D_ + d0 + c]);
    tile[rr][c] = f2bf(x);
  }
  __syncthreads();
  u16* out = Vt + ((size_t)(b * NKV_ + kh) * D_ + d0) * T_ + t0;
#pragma unroll
  for (int i = 0; i < 16; ++i) {
    int rr = r4 * 16 + i;                  // d offset
    out[(size_t)rr * T_ + c] = tile[c][rr];
  }
}

// ---------------- flash attention (2-phase prefetch double-buffer) ----------------
// Grid (S/128, NQ, B). 4 waves x 32 q-rows. KV tiles of 64, double-buffered:
// tile t+1's global_load_lds issued BEFORE compute(t); raw s_barrier + counted
// s_waitcnt vmcnt(8) keeps the prefetch in flight across the barrier (T3/T4).
// Defer-max (T13, THR=8) skips O-rescale when max doesn't grow. setprio (T5)
// around MFMA clusters.
__global__ __launch_bounds__(256, 2)
void k_attn(const u16* __restrict__ Q, const u16* __restrict__ Kall,
            const u16* __restrict__ Vt, u16* __restrict__ O) {
  __shared__ __align__(16) u16 Ks[2][64 * 128];   // [t][d] 2x16KB
  __shared__ __align__(16) u16 Vs[2][128 * 64];   // [d][t] 2x16KB
  __shared__ __align__(16) u16 Ps[4][32 * 64];    // per-wave P, 4x4KB  (total 80KB)
  const int sb = blockIdx.x;       // 0..7
  const int h  = blockIdx.y;       // 0..31
  const int b  = blockIdx.z;       // 0..1
  const int kh = h >> 2;           // GQA: G=4
  const int tid = threadIdx.x;
  const int lane = tid & 63, wv = tid >> 6;
  const int l15 = lane & 15, l4 = lane >> 4;
  const int s0 = sb * 128;
  const int rowbase = s0 + wv * 32;

  const u16* kbase = Kall + (size_t)(b * NKV_ + kh) * T_ * D_;
  const u16* vbase = Vt   + (size_t)(b * NKV_ + kh) * D_ * T_;
  const int ntiles = min(32, 2 * sb + 18);   // last t = s0+127+P

  // chunk decomposition for staging (wave-uniform LDS base + lane*16)
  int kr[4], kc[4], vr[4], vc[4];
#pragma unroll
  for (int i = 0; i < 4; ++i) {
    int chunk = tid + i * 256;
    kr[i] = chunk >> 4; kc[i] = (chunk & 15) ^ (kr[i] & 7);
    vr[i] = chunk >> 3; vc[i] = (chunk & 7)  ^ (vr[i] & 7);
  }
  auto stage = [&](int buf, int t0) {
#pragma unroll
    for (int i = 0; i < 4; ++i) {
      int chunk = tid + i * 256;
      gload16(kbase + (size_t)(t0 + kr[i]) * D_ + kc[i] * 8, &Ks[buf][chunk * 8]);
      gload16(vbase + (size_t)vr[i] * T_ + t0 + vc[i] * 8,  &Vs[buf][chunk * 8]);
    }
  };

  // Q frags held in registers for the whole KV loop (Q pre-scaled by 1/sqrt(D))
  const u16* qbase = Q + (size_t)(b * NQ_ + h) * S_ * D_;
  bf16x8 qf[2][4];
#pragma unroll
  for (int mt = 0; mt < 2; ++mt)
#pragma unroll
    for (int ks = 0; ks < 4; ++ks)
      qf[mt][ks] = *(const bf16x8*)(qbase + (size_t)(rowbase + mt * 16 + l15) * D_ + ks * 32 + l4 * 8);

  f32x4 acco[2][8] = {};
  float mrun[2][4], lrun[2][4];
#pragma unroll
  for (int mt = 0; mt < 2; ++mt)
#pragma unroll
    for (int i = 0; i < 4; ++i) { mrun[mt][i] = -1e30f; lrun[mt][i] = 0.f; }

  stage(0, 0);   // prologue prefetch (8 loads in flight)

  for (int tt = 0; tt < ntiles; ++tt) {
    const int cur = tt & 1;
    const int t0 = tt * 64;
    // issue NEXT tile's loads, then wait only for CURRENT tile's 8 (counted vmcnt)
    if (tt + 1 < ntiles) {
      stage(cur ^ 1, (tt + 1) * 64);
      asm volatile("s_waitcnt vmcnt(8)" ::: "memory");
    } else {
      asm volatile("s_waitcnt vmcnt(0)" ::: "memory");
    }
    __builtin_amdgcn_sched_barrier(0);   // rule #18: fence reads below the waitcnt
    __builtin_amdgcn_s_barrier();        // all waves: tile-tt data visible
    __builtin_amdgcn_sched_barrier(0);

    // S = Q @ K^T  (32 MFMAs, 16 swizzled ds_read_b128)
    f32x4 accs[2][4] = {};
    __builtin_amdgcn_s_setprio(1);
#pragma unroll
    for (int tb = 0; tb < 4; ++tb) {
      int r = tb * 16 + l15;
#pragma unroll
      for (int ks = 0; ks < 4; ++ks) {
        int cc = (ks * 4 + l4) ^ (r & 7);
        bf16x8 kf = *(const bf16x8*)(&Ks[cur][r * 128 + cc * 8]);
#pragma unroll
        for (int mt = 0; mt < 2; ++mt)
          accs[mt][tb] = __builtin_amdgcn_mfma_f32_16x16x32_bf16(qf[mt][ks], kf, accs[mt][tb], 0, 0, 0);
      }
    }
    __builtin_amdgcn_s_setprio(0);
    // causal mask (only last two tiles can be partial: P,S multiples of 64)
    if (tt >= 2 * sb + 16) {
#pragma unroll
      for (int mt = 0; mt < 2; ++mt)
#pragma unroll
        for (int tb = 0; tb < 4; ++tb)
#pragma unroll
          for (int i = 0; i < 4; ++i) {
            int srow = rowbase + mt * 16 + l4 * 4 + i;
            int tcol = t0 + tb * 16 + l15;
            if (tcol > srow + P_) accs[mt][tb][i] = -1e30f;
          }
    }
    // online softmax (rows live in 16 consecutive lanes -> shfl_xor 1,2,4,8)
#pragma unroll
    for (int mt = 0; mt < 2; ++mt) {
      float vmax[4];
#pragma unroll
      for (int i = 0; i < 4; ++i) {
        float v = fmaxf(fmaxf(accs[mt][0][i], accs[mt][1][i]),
                        fmaxf(accs[mt][2][i], accs[mt][3][i]));
        v = fmaxf(v, __shfl_xor(v, 1));
        v = fmaxf(v, __shfl_xor(v, 2));
        v = fmaxf(v, __shfl_xor(v, 4));
        v = fmaxf(v, __shfl_xor(v, 8));
        vmax[i] = v;
      }
      // defer-max (T13): skip rescale when all rows' max growth <= 8
      bool ok = true;
#pragma unroll
      for (int i = 0; i < 4; ++i) ok = ok && (vmax[i] <= mrun[mt][i] + 8.f);
      if (!__all(ok)) {
#pragma unroll
        for (int i = 0; i < 4; ++i) {
          float mn = fmaxf(mrun[mt][i], vmax[i]);
          float al = __expf(mrun[mt][i] - mn);
          mrun[mt][i] = mn;
          lrun[mt][i] *= al;
#pragma unroll
          for (int db = 0; db < 8; ++db)
            acco[mt][db][i] *= al;
        }
      }
      float rs[4] = {0.f, 0.f, 0.f, 0.f};
#pragma unroll
      for (int tb = 0; tb < 4; ++tb)
#pragma unroll
        for (int i = 0; i < 4; ++i) {
          float p = __expf(accs[mt][tb][i] - mrun[mt][i]);
          accs[mt][tb][i] = p;
          rs[i] += p;
        }
#pragma unroll
      for (int i = 0; i < 4; ++i) {
        rs[i] += __shfl_xor(rs[i], 1);
        rs[i] += __shfl_xor(rs[i], 2);
        rs[i] += __shfl_xor(rs[i], 4);
        rs[i] += __shfl_xor(rs[i], 8);
        lrun[mt][i] += rs[i];
      }
      // P (D-layout) -> swizzled per-wave LDS, re-read as A-frags
#pragma unroll
      for (int tb = 0; tb < 4; ++tb)
#pragma unroll
        for (int i = 0; i < 4; ++i) {
          int r = mt * 16 + l4 * 4 + i;
          int col = tb * 16 + l15;
          int cc = (col >> 3) ^ (r & 7);
          Ps[wv][r * 64 + cc * 8 + (col & 7)] = f2bf(accs[mt][tb][i]);
        }
    }
    // O += P @ V   (per-wave LDS: same-wave DS ops in-order; no barrier needed)
    __builtin_amdgcn_s_setprio(1);
#pragma unroll
    for (int ks = 0; ks < 2; ++ks) {
      bf16x8 pf[2];
#pragma unroll
      for (int mt = 0; mt < 2; ++mt) {
        int r = mt * 16 + l15;
        int cc = (ks * 4 + l4) ^ (r & 7);
        pf[mt] = *(const bf16x8*)(&Ps[wv][r * 64 + cc * 8]);
      }
#pragma unroll
      for (int db = 0; db < 8; ++db) {
        int r = db * 16 + l15;
        int cc = (ks * 4 + l4) ^ (r & 7);
        bf16x8 vf = *(const bf16x8*)(&Vs[cur][r * 64 + cc * 8]);
#pragma unroll
        for (int mt = 0; mt < 2; ++mt)
          acco[mt][db] = __builtin_amdgcn_mfma_f32_16x16x32_bf16(pf[mt], vf, acco[mt][db], 0, 0, 0);
      }
    }
    __builtin_amdgcn_s_setprio(0);
    // all waves done reading buf[cur] before next iter stages into it
    __builtin_amdgcn_sched_barrier(0);
    __builtin_amdgcn_s_barrier();
    __builtin_amdgcn_sched_barrier(0);
  }
  // epilogue: O / l, -> bf16 attn_out [B*S][NQ*D]
#pragma unroll
  for (int mt = 0; mt < 2; ++mt)
#pragma unroll
    for (int db = 0; db < 8; ++db)
#pragma unroll
      for (int i = 0; i < 4; ++i) {
        int srow = rowbase + mt * 16 + l4 * 4 + i;
        int d = db * 16 + l15;
        float o = acco[mt][db][i] / lrun[mt][i];
        O[(size_t)(b * S_ + srow) * (NQ_ * D_) + h * D_ + d] = f2bf(o);
      }
}

// ---------------- launcher ----------------
extern "C" void kernel_launch(void* const* d_in, const int* in_sizes, int n_in,
                              void* d_out, int out_size, void* d_ws, size_t ws_size,
                              hipStream_t stream) {
  const float* hidden = (const float*)d_in[0];  // [2,1024,4096]
  const float* w_qkv  = (const float*)d_in[1];  // [4096,6144]
  const float* w_o    = (const float*)d_in[2];  // [4096,4096]
  const float* cosb   = (const float*)d_in[3];  // [1024,128]
  const float* sinb   = (const float*)d_in[4];
  const float* kc     = (const float*)d_in[5];  // [2,1024,8,128]
  const float* vc     = (const float*)d_in[6];
  float* out = (float*)d_out;                   // [2,1024,4096] fp32

  // workspace layout (bytes). wot reuses [hid|qkv-head] region — both dead
  // by the time k_wtrans(w_o) runs (same-stream serialization).
  char* ws = (char*)d_ws;
  u16* wqkvt = (u16*)(ws + 0);           // 6144*4096*2 = 50331648
  u16* hid   = (u16*)(ws + 50331648);    // 2048*4096*2 = 16777216
  u16* qkv   = (u16*)(ws + 67108864);    // 2048*6144*2 = 25165824
  u16* wot   = (u16*)(ws + 50331648);    // 4096*4096*2 = 33554432 (reuse)
  u16* qrope = (u16*)(ws + 92274688);    // 16777216
  u16* kall  = (u16*)(ws + 109051904);   // 8388608
  u16* vallt = (u16*)(ws + 117440512);   // 8388608
  u16* attno = (u16*)(ws + 125829120);   // 16777216  (total 142606336 B)

  k_wtrans<<<dim3(QKVN_ / 64, H_ / 64), 256, 0, stream>>>(w_qkv, wqkvt, H_, QKVN_);
  k_f32_to_bf16<<<(B_ * S_ * H_ / 4 + 255) / 256, 256, 0, stream>>>(hidden, hid, B_ * S_ * H_ / 4);
  k_gemm<true><<<dim3(QKVN_ / 128, (B_ * S_) / 128), 256, 0, stream>>>(
      hid, wqkvt, qkv, B_ * S_, QKVN_, H_);
  k_rope_scatter<<<2048, 256, 0, stream>>>(qkv, cosb, sinb, kc, qrope, kall);
  k_vbuild<<<dim3(T_ / 64, D_ / 64, B_ * NKV_), 256, 0, stream>>>(qkv, vc, vallt);
  k_wtrans<<<dim3(H_ / 64, H_ / 64), 256, 0, stream>>>(w_o, wot, H_, H_);
  k_attn<<<dim3(S_ / 128, NQ_, B_), 256, 0, stream>>>(qrope, kall, vallt, attno);
  k_gemm<false><<<dim3(H_ / 128, (B_ * S_) / 128), 256, 0, stream>>>(
      attno, wot, out, B_ * S_, H_, H_);
}

// Round 5
// 514.750 us; speedup vs baseline: 1.1247x; 1.0787x over previous
//
#include <hip/hip_runtime.h>
#include <hip/hip_bf16.h>
#include <cstdint>
#include <cstddef>

// Problem constants (LlamaAttention: B=2,S=1024,P=1024,H=4096,NQ=32,NKV=8,D=128)
#define B_    2
#define S_    1024
#define P_    1024
#define T_    2048      // P + S
#define H_    4096
#define NQ_   32
#define NKV_  8
#define D_    128
#define QKVN_ 6144      // (NQ + 2*NKV) * D
#define SCALE_ 0.08838834764831845f  // 1/sqrt(128)

typedef unsigned short u16;
typedef unsigned int   u32;
typedef short  bf16x8 __attribute__((ext_vector_type(8)));   // 8 bf16 = 4 VGPR (MFMA A/B frag)
typedef float  f32x4  __attribute__((ext_vector_type(4)));   // 16x16 MFMA C/D frag
typedef float  f32x16 __attribute__((ext_vector_type(16)));  // 32x32 MFMA C/D frag

__device__ __forceinline__ float bf2f(u16 u) {
  union { unsigned u; float f; } x; x.u = ((unsigned)u) << 16; return x.f;
}
__device__ __forceinline__ u16 f2bf(float f) {
  union { float f; unsigned u; } x; x.f = f;
  unsigned r = (x.u + 0x7fffu + ((x.u >> 16) & 1u)) >> 16;   // RNE
  return (u16)r;
}
// HW packed f32->bf16 (no builtin on gfx950; guide T12 recipe)
__device__ __forceinline__ u32 cvtpk_bf16(float lo, float hi) {
  u32 r;
  asm("v_cvt_pk_bf16_f32 %0, %1, %2" : "=v"(r) : "v"(lo), "v"(hi));
  return r;
}

// async global->LDS, 16B per lane. LDS dest must be wave-uniform base + lane*16
// (chunk = tid + i*256 guarantees per-lane LDS addr = firstlane_base + lane*16).
// Global src IS per-lane -> source-side XOR swizzle works (m173 pattern).
__device__ __forceinline__ void gload16(const void* g, void* l) {
  __builtin_amdgcn_global_load_lds(
      (const __attribute__((address_space(1))) unsigned int*)g,
      (__attribute__((address_space(3))) unsigned int*)l, 16, 0, 0);
}

// ---------------- hidden f32 -> bf16 ----------------
__global__ void k_f32_to_bf16(const float* __restrict__ in, u16* __restrict__ out, int n4) {
  int i = blockIdx.x * blockDim.x + threadIdx.x;
  if (i >= n4) return;
  float4 v = ((const float4*)in)[i];
  union { u16 s[4]; uint2 v; } o;
  o.s[0] = f2bf(v.x); o.s[1] = f2bf(v.y); o.s[2] = f2bf(v.z); o.s[3] = f2bf(v.w);
  ((uint2*)out)[i] = o.v;
}

// ---------------- w[K][N] f32 -> wt[N][K] bf16 (64x64 LDS tile transpose) ----------------
__global__ void k_wtrans(const float* __restrict__ w, u16* __restrict__ wt, int K, int N) {
  __shared__ __align__(16) u16 tile[64][66];   // pad 66: conflict-free column reads
  const int n0 = blockIdx.x * 64;
  const int k0 = blockIdx.y * 64;
  const int tid = threadIdx.x;
  const int c = tid & 63;
  const int r4 = tid >> 6;
#pragma unroll
  for (int i = 0; i < 16; ++i) {
    int rr = r4 * 16 + i;
    tile[rr][c] = f2bf(w[(size_t)(k0 + rr) * N + n0 + c]);
  }
  __syncthreads();
#pragma unroll
  for (int i = 0; i < 16; ++i) {
    int rr = r4 * 16 + i;
    wt[(size_t)(n0 + rr) * K + k0 + c] = tile[c][rr];
  }
}

// ---------------- GEMM: C[M,N] = A[M,K](bf16) @ Bt[N,K](bf16)^T, fp32 accum ----------------
// 128x128 tile, BK=64, 4 waves (2x2), each wave 64x64 via 4x4 frags of 16x16x32.
// (unchanged this round)
template<bool BF16OUT>
__global__ __launch_bounds__(256, 2)
void k_gemm(const u16* __restrict__ A, const u16* __restrict__ Bt,
            void* __restrict__ Cv, int M, int N, int K) {
  __shared__ __align__(16) u16 As[128 * 64];   // 16KB, rows 128B = 8 chunks of 16B
  __shared__ __align__(16) u16 Bs[128 * 64];
  const int tid = threadIdx.x;
  const int lane = tid & 63;
  const int wv = tid >> 6;
  const int wm = wv >> 1, wn = wv & 1;
  const int m0 = blockIdx.y * 128;
  const int n0 = blockIdx.x * 128;
  const int l15 = lane & 15, l4 = lane >> 4;

  f32x4 acc[4][4] = {};
  const int nk = K >> 6;
  int srow[4], scol[4];
#pragma unroll
  for (int i = 0; i < 4; ++i) {
    int chunk = tid + i * 256;           // 1024 chunks per tile
    srow[i] = chunk >> 3;
    scol[i] = (chunk & 7) ^ (srow[i] & 7);
  }
  for (int kt = 0; kt < nk; ++kt) {
    __syncthreads();
#pragma unroll
    for (int i = 0; i < 4; ++i) {
      int chunk = tid + i * 256;
      gload16(A  + (size_t)(m0 + srow[i]) * K + kt * 64 + scol[i] * 8, &As[chunk * 8]);
      gload16(Bt + (size_t)(n0 + srow[i]) * K + kt * 64 + scol[i] * 8, &Bs[chunk * 8]);
    }
    __syncthreads();
    bf16x8 af[4][2], bfr[4][2];
#pragma unroll
    for (int mt = 0; mt < 4; ++mt) {
      int r = wm * 64 + mt * 16 + l15;
#pragma unroll
      for (int ks = 0; ks < 2; ++ks) {
        int cc = (ks * 4 + l4) ^ (r & 7);
        af[mt][ks] = *(const bf16x8*)(&As[r * 64 + cc * 8]);
      }
    }
#pragma unroll
    for (int nt = 0; nt < 4; ++nt) {
      int r = wn * 64 + nt * 16 + l15;
#pragma unroll
      for (int ks = 0; ks < 2; ++ks) {
        int cc = (ks * 4 + l4) ^ (r & 7);
        bfr[nt][ks] = *(const bf16x8*)(&Bs[r * 64 + cc * 8]);
      }
    }
#pragma unroll
    for (int mt = 0; mt < 4; ++mt)
#pragma unroll
      for (int nt = 0; nt < 4; ++nt)
#pragma unroll
        for (int ks = 0; ks < 2; ++ks)
          acc[mt][nt] = __builtin_amdgcn_mfma_f32_16x16x32_bf16(
              af[mt][ks], bfr[nt][ks], acc[mt][nt], 0, 0, 0);
  }
#pragma unroll
  for (int mt = 0; mt < 4; ++mt)
#pragma unroll
    for (int nt = 0; nt < 4; ++nt)
#pragma unroll
      for (int i = 0; i < 4; ++i) {
        int row = m0 + wm * 64 + mt * 16 + l4 * 4 + i;
        int col = n0 + wn * 64 + nt * 16 + l15;
        size_t off = (size_t)row * N + col;
        if (BF16OUT) ((u16*)Cv)[off] = f2bf(acc[mt][nt][i]);
        else         ((float*)Cv)[off] = acc[mt][nt][i];
      }
}

// ---------------- RoPE + scatter into head-major layouts ----------------
__global__ void k_rope_scatter(const u16* __restrict__ qkv,
                               const float* __restrict__ cosb, const float* __restrict__ sinb,
                               const float* __restrict__ kcache,
                               u16* __restrict__ Q, u16* __restrict__ Kall) {
  const int gsz = gridDim.x * blockDim.x;
  const int i0 = blockIdx.x * blockDim.x + threadIdx.x;
  for (int i = i0; i < B_ * S_ * NQ_ * 64; i += gsz) {
    int d = i & 63, hh = (i >> 6) & 31, s = (i >> 11) & 1023, b = i >> 21;
    const u16* row = qkv + (size_t)(b * S_ + s) * QKVN_ + hh * D_;
    float x1 = bf2f(row[d]), x2 = bf2f(row[d + 64]);
    float c = cosb[s * D_ + d], sn = sinb[s * D_ + d];
    u16* q = Q + (size_t)((b * NQ_ + hh) * S_ + s) * D_;
    q[d]      = f2bf((x1 * c - x2 * sn) * SCALE_);
    q[d + 64] = f2bf((x2 * c + x1 * sn) * SCALE_);
  }
  for (int i = i0; i < B_ * S_ * NKV_ * 64; i += gsz) {
    int d = i & 63, kh = (i >> 6) & 7, s = (i >> 9) & 1023, b = i >> 19;
    const u16* row = qkv + (size_t)(b * S_ + s) * QKVN_ + NQ_ * D_ + kh * D_;
    float x1 = bf2f(row[d]), x2 = bf2f(row[d + 64]);
    float c = cosb[s * D_ + d], sn = sinb[s * D_ + d];
    u16* kd = Kall + (size_t)((b * NKV_ + kh) * T_ + P_ + s) * D_;
    kd[d]      = f2bf(x1 * c - x2 * sn);
    kd[d + 64] = f2bf(x2 * c + x1 * sn);
  }
  for (int i = i0; i < B_ * P_ * NKV_ * D_; i += gsz) {
    int d = i & 127, kh = (i >> 7) & 7, t = (i >> 10) & 1023, b = i >> 20;
    float x = kcache[(size_t)((b * P_ + t) * NKV_ + kh) * D_ + d];
    Kall[(size_t)((b * NKV_ + kh) * T_ + t) * D_ + d] = f2bf(x);
  }
}

// ---------------- V -> transposed Vt[B][NKV][D][T] (64x64 LDS tile transpose) ----------------
__global__ void k_vbuild(const u16* __restrict__ qkv, const float* __restrict__ vcache,
                         u16* __restrict__ Vt) {
  __shared__ __align__(16) u16 tile[64][66];
  const int t0 = blockIdx.x * 64;
  const int d0 = blockIdx.y * 64;
  const int bkh = blockIdx.z;
  const int b = bkh >> 3, kh = bkh & 7;
  const int tid = threadIdx.x;
  const int c = tid & 63, r4 = tid >> 6;
#pragma unroll
  for (int i = 0; i < 16; ++i) {
    int rr = r4 * 16 + i;
    int t = t0 + rr;
    float x;
    if (t < P_) x = vcache[(size_t)((b * P_ + t) * NKV_ + kh) * D_ + d0 + c];
    else        x = bf2f(qkv[(size_t)(b * S_ + (t - P_)) * QKVN_ + (NQ_ + NKV_) * D_ + kh * D_ + d0 + c]);
    tile[rr][c] = f2bf(x);
  }
  __syncthreads();
  u16* out = Vt + ((size_t)(b * NKV_ + kh) * D_ + d0) * T_ + t0;
#pragma unroll
  for (int i = 0; i < 16; ++i) {
    int rr = r4 * 16 + i;                  // d offset
    out[(size_t)rr * T_ + c] = tile[c][rr];
  }
}

// ---------------- flash attention: swapped-QK^T, 32x32x16 MFMA (m214 SSB structure) ----------
// Grid (S/128, NQ, B). 4 waves x 32 q-rows. KV tiles of 64, double-buffered with
// counted vmcnt(8) prefetch (validated round-4 skeleton).
// S^T = mfma(A=K, B=Q): D col = lane&31 = q-row -> softmax row is LANE-LOCAL
// (per-lane scalar m/l, 1 shfl_xor(32) per reduce). P stays in registers:
// cvt_pk_bf16 + partner-exchange builds PV A-frags (T12). No P LDS buffer.
// 32x32 C/D layout [m74/m101]: col=lane&31, row=(reg&3)+8*(reg>>2)+4*(lane>>5).
// A-frag assumed row=lane&31, k=(lane>>5)*8+j (extrapolated from our validated
// 16x16 pattern row=lane&15,k=(lane>>4)*8+j).
__global__ __launch_bounds__(256, 2)
void k_attn(const u16* __restrict__ Q, const u16* __restrict__ Kall,
            const u16* __restrict__ Vt, u16* __restrict__ O) {
  __shared__ __align__(16) u16 Ks[2][64 * 128];   // [t][d] 2x16KB
  __shared__ __align__(16) u16 Vs[2][128 * 64];   // [d][t] 2x16KB
  __shared__ float bcast[4 * 32];                  // per-wave per-q broadcast
  const int sb = blockIdx.x;       // 0..7
  const int h  = blockIdx.y;       // 0..31
  const int b  = blockIdx.z;       // 0..1
  const int kh = h >> 2;           // GQA: G=4
  const int tid = threadIdx.x;
  const int lane = tid & 63, wv = tid >> 6;
  const int l31 = lane & 31, hi = lane >> 5;
  const int s0 = sb * 128;
  const int rowbase = s0 + wv * 32;
  const int qrow = rowbase + l31;          // this lane's softmax row

  const u16* kbase = Kall + (size_t)(b * NKV_ + kh) * T_ * D_;
  const u16* vbase = Vt   + (size_t)(b * NKV_ + kh) * D_ * T_;
  const int ntiles = min(32, 2 * sb + 18);   // last t = s0+127+P

  // chunk decomposition for staging (wave-uniform LDS base + lane*16)
  int kr[4], kc[4], vr[4], vc[4];
#pragma unroll
  for (int i = 0; i < 4; ++i) {
    int chunk = tid + i * 256;
    kr[i] = chunk >> 4; kc[i] = (chunk & 15) ^ (kr[i] & 7);
    vr[i] = chunk >> 3; vc[i] = (chunk & 7)  ^ (vr[i] & 7);
  }
  auto stage = [&](int buf, int t0) {
#pragma unroll
    for (int i = 0; i < 4; ++i) {
      int chunk = tid + i * 256;
      gload16(kbase + (size_t)(t0 + kr[i]) * D_ + kc[i] * 8, &Ks[buf][chunk * 8]);
      gload16(vbase + (size_t)vr[i] * T_ + t0 + vc[i] * 8,  &Vs[buf][chunk * 8]);
    }
  };

  // Q held in registers: B-frag needs Q[q=l31][d=ds*16+hi*8+j] (contiguous 16B)
  const u16* qbase = Q + (size_t)(b * NQ_ + h) * S_ * D_ + (size_t)qrow * D_;
  bf16x8 qf[8];
#pragma unroll
  for (int ds_ = 0; ds_ < 8; ++ds_)
    qf[ds_] = *(const bf16x8*)(qbase + ds_ * 16 + hi * 8);

  f32x16 acco[4] = {};                // O^T frags: [dblk] col=d, row=q
  float mrun = -1e30f, lrun = 0.f;    // per-lane scalars for q-row `qrow`

  stage(0, 0);   // prologue prefetch (8 loads in flight)

  for (int tt = 0; tt < ntiles; ++tt) {
    const int cur = tt & 1;
    const int t0 = tt * 64;
    if (tt + 1 < ntiles) {
      stage(cur ^ 1, (tt + 1) * 64);
      asm volatile("s_waitcnt vmcnt(8)" ::: "memory");
    } else {
      asm volatile("s_waitcnt vmcnt(0)" ::: "memory");
    }
    __builtin_amdgcn_sched_barrier(0);
    __builtin_amdgcn_s_barrier();        // all waves: tile-tt data visible
    __builtin_amdgcn_sched_barrier(0);

    // S^T = K @ Q : accs[tb] = S[kv=tb*32+crow][q=l31], 16 MFMAs of 32x32x16
    f32x16 accs[2] = {};
    __builtin_amdgcn_s_setprio(1);
#pragma unroll
    for (int tb = 0; tb < 2; ++tb) {
      int r = tb * 32 + l31;
#pragma unroll
      for (int ds_ = 0; ds_ < 8; ++ds_) {
        int cc = (ds_ * 2 + hi) ^ (r & 7);
        bf16x8 kf = *(const bf16x8*)(&Ks[cur][r * 128 + cc * 8]);
        accs[tb] = __builtin_amdgcn_mfma_f32_32x32x16_bf16(kf, qf[ds_], accs[tb], 0, 0, 0);
      }
    }
    __builtin_amdgcn_s_setprio(0);

    // causal mask (kv = t0 + tb*32 + crow(reg,hi); mask kv > qrow + P)
    if (tt >= 2 * sb + 16) {
#pragma unroll
      for (int tb = 0; tb < 2; ++tb)
#pragma unroll
        for (int reg = 0; reg < 16; ++reg) {
          int kv = t0 + tb * 32 + (reg & 3) + 8 * (reg >> 2) + 4 * hi;
          if (kv > qrow + P_) accs[tb][reg] = -1e30f;
        }
    }

    // row max: 31 in-lane fmax + one partner exchange
    float m = accs[0][0];
#pragma unroll
    for (int reg = 1; reg < 16; ++reg) m = fmaxf(m, accs[0][reg]);
#pragma unroll
    for (int reg = 0; reg < 16; ++reg) m = fmaxf(m, accs[1][reg]);
    m = fmaxf(m, __shfl_xor(m, 32));

    // defer-max (T13): rescale O only when max grows past threshold
    if (!__all(m <= mrun + 8.f)) {
      float mn = fmaxf(mrun, m);
      float al = __expf(mrun - mn);
      mrun = mn; lrun *= al;
      if (hi == 0) bcast[wv * 32 + l31] = al;   // same-wave DS: ordered, no barrier
      float alq[16];
#pragma unroll
      for (int reg = 0; reg < 16; ++reg)
        alq[reg] = bcast[wv * 32 + (reg & 3) + 8 * (reg >> 2) + 4 * hi];
#pragma unroll
      for (int dblk = 0; dblk < 4; ++dblk)
#pragma unroll
        for (int reg = 0; reg < 16; ++reg)
          acco[dblk][reg] *= alq[reg];
    }

    // exp + row sum (scalar per lane)
    float rs = 0.f;
#pragma unroll
    for (int tb = 0; tb < 2; ++tb)
#pragma unroll
      for (int reg = 0; reg < 16; ++reg) {
        float p = __expf(accs[tb][reg] - mrun);
        accs[tb][reg] = p;
        rs += p;
      }
    lrun += rs + __shfl_xor(rs, 32);

    // P -> bf16 A-frags (cvt_pk + partner exchange) fused with PV MFMAs.
    // For ks (16 kv): lane needs P[q=l31][kv=ks*16+hi*8+j], j=0..7.
    __builtin_amdgcn_s_setprio(1);
#pragma unroll
    for (int tb = 0; tb < 2; ++tb) {
#pragma unroll
      for (int half = 0; half < 2; ++half) {
        const int bx = half * 8;
        u32 xa = cvtpk_bf16(accs[tb][bx + 0], accs[tb][bx + 1]);  // kv off (0,1)|(4,5)
        u32 xb = cvtpk_bf16(accs[tb][bx + 2], accs[tb][bx + 3]);  // (2,3)|(6,7)
        u32 ya = cvtpk_bf16(accs[tb][bx + 4], accs[tb][bx + 5]);  // (8,9)|(12,13)
        u32 yb = cvtpk_bf16(accs[tb][bx + 6], accs[tb][bx + 7]);  // (10,11)|(14,15)
        u32 sxa = __shfl_xor(xa, 32), sxb = __shfl_xor(xb, 32);
        u32 sya = __shfl_xor(ya, 32), syb = __shfl_xor(yb, 32);
        union { u32 w[4]; bf16x8 v; } pa;
        pa.w[0] = hi ? sya : xa;   // j(0,1):  hi0 kv0,1  | hi1 kv8,9
        pa.w[1] = hi ? syb : xb;   // j(2,3)
        pa.w[2] = hi ? ya  : sxa;  // j(4,5):  hi0 kv4,5(partner) | hi1 kv12,13
        pa.w[3] = hi ? yb  : sxb;  // j(6,7)
        const int ks = tb * 2 + half;
#pragma unroll
        for (int dblk = 0; dblk < 4; ++dblk) {
          int r2 = dblk * 32 + l31;
          int cc = (ks * 2 + hi) ^ (r2 & 7);
          bf16x8 vfr = *(const bf16x8*)(&Vs[cur][r2 * 64 + cc * 8]);
          acco[dblk] = __builtin_amdgcn_mfma_f32_32x32x16_bf16(pa.v, vfr, acco[dblk], 0, 0, 0);
        }
      }
    }
    __builtin_amdgcn_s_setprio(0);

    // all waves done reading buf[cur] before next iter stages into it
    __builtin_amdgcn_sched_barrier(0);
    __builtin_amdgcn_s_barrier();
    __builtin_amdgcn_sched_barrier(0);
  }

  // epilogue: O[q][d] = acco / l ; q = rowbase+crow(reg,hi), d = dblk*32+l31
  if (hi == 0) bcast[wv * 32 + l31] = 1.0f / lrun;
  float linv[16];
#pragma unroll
  for (int reg = 0; reg < 16; ++reg)
    linv[reg] = bcast[wv * 32 + (reg & 3) + 8 * (reg >> 2) + 4 * hi];
#pragma unroll
  for (int dblk = 0; dblk < 4; ++dblk)
#pragma unroll
    for (int reg = 0; reg < 16; ++reg) {
      int q = rowbase + (reg & 3) + 8 * (reg >> 2) + 4 * hi;
      O[(size_t)(b * S_ + q) * (NQ_ * D_) + h * D_ + dblk * 32 + l31] =
          f2bf(acco[dblk][reg] * linv[reg]);
    }
}

// ---------------- launcher ----------------
extern "C" void kernel_launch(void* const* d_in, const int* in_sizes, int n_in,
                              void* d_out, int out_size, void* d_ws, size_t ws_size,
                              hipStream_t stream) {
  const float* hidden = (const float*)d_in[0];  // [2,1024,4096]
  const float* w_qkv  = (const float*)d_in[1];  // [4096,6144]
  const float* w_o    = (const float*)d_in[2];  // [4096,4096]
  const float* cosb   = (const float*)d_in[3];  // [1024,128]
  const float* sinb   = (const float*)d_in[4];
  const float* kc     = (const float*)d_in[5];  // [2,1024,8,128]
  const float* vc     = (const float*)d_in[6];
  float* out = (float*)d_out;                   // [2,1024,4096] fp32

  char* ws = (char*)d_ws;
  u16* wqkvt = (u16*)(ws + 0);           // 6144*4096*2 = 50331648
  u16* hid   = (u16*)(ws + 50331648);    // 2048*4096*2 = 16777216
  u16* qkv   = (u16*)(ws + 67108864);    // 2048*6144*2 = 25165824
  u16* wot   = (u16*)(ws + 50331648);    // 4096*4096*2 = 33554432 (reuse)
  u16* qrope = (u16*)(ws + 92274688);    // 16777216
  u16* kall  = (u16*)(ws + 109051904);   // 8388608
  u16* vallt = (u16*)(ws + 117440512);   // 8388608
  u16* attno = (u16*)(ws + 125829120);   // 16777216  (total 142606336 B)

  k_wtrans<<<dim3(QKVN_ / 64, H_ / 64), 256, 0, stream>>>(w_qkv, wqkvt, H_, QKVN_);
  k_f32_to_bf16<<<(B_ * S_ * H_ / 4 + 255) / 256, 256, 0, stream>>>(hidden, hid, B_ * S_ * H_ / 4);
  k_gemm<true><<<dim3(QKVN_ / 128, (B_ * S_) / 128), 256, 0, stream>>>(
      hid, wqkvt, qkv, B_ * S_, QKVN_, H_);
  k_rope_scatter<<<2048, 256, 0, stream>>>(qkv, cosb, sinb, kc, qrope, kall);
  k_vbuild<<<dim3(T_ / 64, D_ / 64, B_ * NKV_), 256, 0, stream>>>(qkv, vc, vallt);
  k_wtrans<<<dim3(H_ / 64, H_ / 64), 256, 0, stream>>>(w_o, wot, H_, H_);
  k_attn<<<dim3(S_ / 128, NQ_, B_), 256, 0, stream>>>(qrope, kall, vallt, attno);
  k_gemm<false><<<dim3(H_ / 128, (B_ * S_) / 128), 256, 0, stream>>>(
      attno, wot, out, B_ * S_, H_, H_);
}